// Round 14
// baseline (621.077 us; speedup 1.0000x reference)
//
#include <hip/hip_runtime.h>
#include <hip/hip_bf16.h>

#define H 128
#define RBF 64

typedef __attribute__((ext_vector_type(8))) short bf16x8;
typedef __attribute__((ext_vector_type(4))) float f32x4;

__device__ inline short f2bf(float f) {
  union { float f; unsigned u; } v; v.f = f;
  const unsigned r = (v.u + 0x7FFFu + ((v.u >> 16) & 1u)) >> 16;
  return (short)r;
}

// ---------------------------------------------------------------- utilities
__global__ __launch_bounds__(128) void ln_rows(const float* __restrict__ X,
                                               const float* __restrict__ g,
                                               const float* __restrict__ bb,
                                               float* __restrict__ Y, int N) {
  __shared__ float sh[4];
  const int row = blockIdx.x;
  const int j = threadIdx.x;
  float x = X[(size_t)row * H + j];
  float s = x, q = x * x;
#pragma unroll
  for (int m = 32; m; m >>= 1) {
    s += __shfl_xor(s, m, 64);
    q += __shfl_xor(q, m, 64);
  }
  if ((j & 63) == 0) { sh[(j >> 6) * 2] = s; sh[(j >> 6) * 2 + 1] = q; }
  __syncthreads();
  s = sh[0] + sh[2];
  q = sh[1] + sh[3];
  const float mu = s * 0.0078125f;
  const float var = q * 0.0078125f - mu * mu;
  const float rs = rsqrtf(var + 1e-5f);
  Y[(size_t)row * H + j] = (x - mu) * rs * g[j] + bb[j];
}

// conv_k (o,i,tap) -> MFMA B-frag bf16 directly
__global__ __launch_bounds__(256) void pack_kt(const float* __restrict__ K,
                                               short* __restrict__ Ktb) {
  const int id = blockIdx.x * 256 + threadIdx.x;
  if (id >= 27 * 4 * 8 * 64) return;
  const int l = id & 63;
  int r = id >> 6;
  const int cb = r & 7; r >>= 3;
  const int kb = r & 3;
  const int tap = r >> 2;
  const int o = cb * 16 + (l & 15);
  const int i0 = kb * 32 + (l >> 4) * 8;
  short* out = Ktb + (size_t)id * 8;
#pragma unroll
  for (int j = 0; j < 8; ++j)
    out[j] = f2bf(K[((size_t)o * H + i0 + j) * 27 + tap]);
}

// 3x We[64][128] f32 -> frag-layout bf16 in one launch
__global__ __launch_bounds__(256) void pack_we3(
    const float* __restrict__ We0, const float* __restrict__ We1,
    const float* __restrict__ We2, short* __restrict__ Wb0,
    short* __restrict__ Wb1, short* __restrict__ Wb2) {
  const int id = blockIdx.x * 256 + threadIdx.x;
  if (id >= 3072) return;
  const int which = id >> 10;
  const int i = id & 1023;
  const float* We = which == 0 ? We0 : which == 1 ? We1 : We2;
  short* Web = which == 0 ? Wb0 : which == 1 ? Wb1 : Wb2;
  const int f = i >> 6, l = i & 63;
  const int h = f >> 3, c = f & 7;
  const int col = (c << 4) + (l & 15);
  const int k0 = h * 32 + (l >> 4) * 8;
  short* o = Web + (size_t)i * 8;
#pragma unroll
  for (int j = 0; j < 8; ++j) o[j] = f2bf(We[(k0 + j) * H + col]);
}

// 3x W[128][128] f32 -> B-frag bf16 (frag f = kb*8+cb, kb=0..3)
__global__ __launch_bounds__(256) void pack_w3(
    const float* __restrict__ W0, const float* __restrict__ W1,
    const float* __restrict__ W2, short* __restrict__ Wb0,
    short* __restrict__ Wb1, short* __restrict__ Wb2) {
  const int id = blockIdx.x * 256 + threadIdx.x;
  if (id >= 3 * 2048) return;
  const int which = id >> 11;
  const int i = id & 2047;
  const float* W = which == 0 ? W0 : which == 1 ? W1 : W2;
  short* Wb = which == 0 ? Wb0 : which == 1 ? Wb1 : Wb2;
  const int f = i >> 6, l = i & 63;
  const int kb = f >> 3, cb = f & 7;
  const int col = cb * 16 + (l & 15);
  const int k0 = kb * 32 + (l >> 4) * 8;
  short* o = Wb + (size_t)i * 8;
#pragma unroll
  for (int j = 0; j < 8; ++j) o[j] = f2bf(W[(size_t)(k0 + j) * H + col]);
}

// -------------------------------------- fused 3-set counting-sort (CSR)
__global__ __launch_bounds__(256) void k_hist3(
    const int* __restrict__ d0, const int* __restrict__ d1,
    const int* __restrict__ d2, int E0, int E1, int E2,
    int* __restrict__ cnt, int off1, int off2) {
  int i = blockIdx.x * 256 + threadIdx.x;
  const int stride = gridDim.x * 256;
  const int ET = E0 + E1 + E2;
  for (; i < ET; i += stride) {
    int d, off;
    if (i < E0) { d = d0[i]; off = 0; }
    else if (i < E0 + E1) { d = d1[i - E0]; off = off1; }
    else { d = d2[i - E0 - E1]; off = off2; }
    atomicAdd(&cnt[off + d], 1);
  }
}

__global__ __launch_bounds__(256) void k_blocksum(const int* __restrict__ cnt,
                                                  int* __restrict__ bsum) {
  __shared__ int sh[256];
  const int t = threadIdx.x;
  sh[t] = cnt[blockIdx.x * 256 + t];
  __syncthreads();
#pragma unroll
  for (int o = 128; o; o >>= 1) {
    if (t < o) sh[t] += sh[t + o];
    __syncthreads();
  }
  if (!t) bsum[blockIdx.x] = sh[0];
}

__global__ __launch_bounds__(512) void k_scan512(const int* __restrict__ bsum,
                                                 int* __restrict__ bpre, int NB) {
  __shared__ int sh[512];
  const int t = threadIdx.x;
  const int v = (t < NB) ? bsum[t] : 0;
  sh[t] = v;
  __syncthreads();
  for (int o = 1; o < 512; o <<= 1) {
    const int u = (t >= o) ? sh[t - o] : 0;
    __syncthreads();
    sh[t] += u;
    __syncthreads();
  }
  if (t < NB) bpre[t] = sh[t] - v;
}

__global__ __launch_bounds__(256) void k_apply3(
    const int* __restrict__ cnt, const int* __restrict__ bpre,
    int* __restrict__ rp0, int* __restrict__ rp1, int* __restrict__ rp2,
    int* __restrict__ cursor, int N0, int N1, int N2, int S1, int S2) {
  __shared__ int sh[256];
  const int b = blockIdx.x;
  const int t = threadIdx.x;
  const int gi = b * 256 + t;
  const int v = cnt[gi];
  sh[t] = v;
  __syncthreads();
  for (int o = 1; o < 256; o <<= 1) {
    const int u = (t >= o) ? sh[t - o] : 0;
    __syncthreads();
    sh[t] += u;
    __syncthreads();
  }
  int sb, N;
  int* rp;
  if (b < S1) { sb = 0; N = N0; rp = rp0; }
  else if (b < S2) { sb = S1; N = N1; rp = rp1; }
  else { sb = S2; N = N2; rp = rp2; }
  const int excl = sh[t] - v + bpre[b] - bpre[sb];
  const int il = (b - sb) * 256 + t;
  if (il <= N) {
    rp[il] = excl;
    if (il < N) cursor[gi] = excl;
  }
}

// ---- 3-set permute: one 16B record per edge: (src, dst, eid, ew-bits).
// Single scattered int4 store (fewer scattered lines than eapfp+sd, and no
// ea movement here at all — gather reads ea directly via eid).
__global__ __launch_bounds__(256) void k_perm3x(
    const int* __restrict__ d0, const int* __restrict__ s0,
    const float* __restrict__ w0, const int* __restrict__ d1,
    const int* __restrict__ s1, const float* __restrict__ w1,
    const int* __restrict__ d2, const int* __restrict__ s2,
    const float* __restrict__ w2, int E0, int E1, int E2,
    int* __restrict__ cursor, int off1, int off2, int4* __restrict__ sde0,
    int4* __restrict__ sde1, int4* __restrict__ sde2) {
  if (blockIdx.x == 0 && threadIdx.x < 48) {  // tail-tile pads: dump row, w=0
    const int wsel = threadIdx.x >> 4;
    const int j = threadIdx.x & 15;
    int4* sp = wsel == 0 ? sde0 + E0 : wsel == 1 ? sde1 + E1 : sde2 + E2;
    sp[j] = make_int4(0, -1, 0, 0);
  }
  int i = blockIdx.x * 256 + threadIdx.x;
  const int stride = gridDim.x * 256;
  const int ET = E0 + E1 + E2;
  for (; i < ET; i += stride) {
    int e, d, s;
    float w;
    int* cur;
    int4* sde;
    if (i < E0) { e = i; d = d0[e]; s = s0[e]; w = w0[e]; cur = cursor; sde = sde0; }
    else if (i < E0 + E1) { e = i - E0; d = d1[e]; s = s1[e]; w = w1[e]; cur = cursor + off1; sde = sde1; }
    else { e = i - E0 - E1; d = d2[e]; s = s2[e]; w = w2[e]; cur = cursor + off2; sde = sde2; }
    const int p = atomicAdd(&cur[d], 1);
    sde[p] = make_int4(s, d, e, __float_as_int(w));
  }
}

// ------------------------------ projection via MFMA: Y = X @ W (bf16/f32acc)
__global__ __launch_bounds__(256, 2) void proj_mfma(
    const float* __restrict__ X, const short* __restrict__ Wb,
    float* __restrict__ Y, int N) {
  __shared__ short xs[64 * 128];  // bf16, XOR-swizzled rows
  const int row0 = blockIdx.x * 64;
  const int t = threadIdx.x;
  const int w = t >> 6, lane = t & 63;
  const int l15 = lane & 15, lg = lane >> 4;

#pragma unroll
  for (int it = 0; it < 4; ++it) {
    const int gidx = it * 256 + t;
    const int r = gidx >> 4;
    const int ch = (gidx & 15) * 8;
    const int row = row0 + r;
    float4 v0 = make_float4(0.f, 0.f, 0.f, 0.f), v1 = v0;
    if (row < N) {
      const float* src = X + (size_t)row * H + ch;
      v0 = *(const float4*)(src);
      v1 = *(const float4*)(src + 4);
    }
    bf16x8 pk;
    pk[0] = f2bf(v0.x); pk[1] = f2bf(v0.y); pk[2] = f2bf(v0.z); pk[3] = f2bf(v0.w);
    pk[4] = f2bf(v1.x); pk[5] = f2bf(v1.y); pk[6] = f2bf(v1.z); pk[7] = f2bf(v1.w);
    const int byte0 = (r * 256 + ch * 2) ^ ((r & 7) << 4);
    *(bf16x8*)((char*)xs + byte0) = pk;
  }
  __syncthreads();

  const int cb0 = 2 * w;
  bf16x8 bw[4][2];
#pragma unroll
  for (int kb = 0; kb < 4; ++kb)
#pragma unroll
    for (int ci = 0; ci < 2; ++ci)
      bw[kb][ci] = *(const bf16x8*)(Wb + (((size_t)kb * 8 + cb0 + ci) * 64 +
                                          lane) * 8);

  f32x4 C[4][2];
#pragma unroll
  for (int mt = 0; mt < 4; ++mt) {
    C[mt][0] = (f32x4){0.f, 0.f, 0.f, 0.f};
    C[mt][1] = (f32x4){0.f, 0.f, 0.f, 0.f};
  }
#pragma unroll
  for (int kb = 0; kb < 4; ++kb) {
#pragma unroll
    for (int mt = 0; mt < 4; ++mt) {
      const int r = mt * 16 + l15;
      const int byte0 = (r * 256 + kb * 64 + lg * 16) ^ ((r & 7) << 4);
      const bf16x8 A = *(const bf16x8*)((const char*)xs + byte0);
      C[mt][0] = __builtin_amdgcn_mfma_f32_16x16x32_bf16(A, bw[kb][0], C[mt][0], 0, 0, 0);
      C[mt][1] = __builtin_amdgcn_mfma_f32_16x16x32_bf16(A, bw[kb][1], C[mt][1], 0, 0, 0);
    }
  }
#pragma unroll
  for (int mt = 0; mt < 4; ++mt)
#pragma unroll
    for (int j = 0; j < 4; ++j) {
      const int row = row0 + mt * 16 + lg * 4 + j;
      if (row < N) {
        float* yp = Y + (size_t)row * H + cb0 * 16 + l15;
        yp[0] = C[mt][0][j];
        yp[16] = C[mt][1][j];
      }
    }
}

// ----------------------------------------- tiled MFMA edge gather (CSR)
// R14: ea read directly via sde.eid (no eapfp roundtrip). Per tile, lane
// loads its A-row's 16B sde record + 2x32B ea chunks; src/dst/ew for the
// C-rows come via __shfl within 16-lane groups. Issue-early/pack-late
// 2-buffer pipeline (loads consumed 2 iterations after issue).
template <int NPB, bool FUSE_LN>
__global__ __launch_bounds__(256, 3) void gather_mfma(
    const float* __restrict__ P, const short* __restrict__ Web,
    const float* __restrict__ ea, const int4* __restrict__ sde,
    const int* __restrict__ rowptr, int N, const float* __restrict__ base,
    const float* __restrict__ skip, const float* __restrict__ g,
    const float* __restrict__ bb, float* __restrict__ out) {
  constexpr int RSTR = (NPB + 1) * 132;
  constexpr int RPAD = RSTR + ((16 - (RSTR & 31)) & 31);  // ≡16 (mod 32)
  __shared__ float acc[4 * RPAD];
  const int t = threadIdx.x;
  const int w = t >> 6, lane = t & 63;
  const int n0 = blockIdx.x * NPB;
  for (int u = t; u < 4 * RPAD; u += 256) acc[u] = 0.f;
  const int rp0 = rowptr[n0];
  const int rp1 = rowptr[min(n0 + NPB, N)];
  __syncthreads();
  const int q0 = rp0 >> 4;
  const int q1 = (rp1 + 15) >> 4;

  const int c0 = 2 * w;
  const bf16x8 bw0 = *(const bf16x8*)(Web + ((size_t)((0 + c0) * 64 + lane)) * 8);
  const bf16x8 bw1 = *(const bf16x8*)(Web + ((size_t)((8 + c0) * 64 + lane)) * 8);
  const bf16x8 bw2 = *(const bf16x8*)(Web + ((size_t)((1 + c0) * 64 + lane)) * 8);
  const bf16x8 bw3 = *(const bf16x8*)(Web + ((size_t)((9 + c0) * 64 + lane)) * 8);

  const int l15 = lane & 15, lg = lane >> 4, rbase = lg * 4;
  const int col0 = c0 * 16 + l15;
  float* const arep = acc + lg * RPAD;

  // issue loads for tile q into the given stage registers
  auto ISSUE = [&](int q, float4& e0, float4& e1, float4& e2, float4& e3,
                   int4& sp, int4& dp, float4& wq, float* pv) {
    const int4 r4 = sde[(size_t)(q * 16 + l15)];
    const float* er = ea + (size_t)r4.z * RBF + lg * 8;
    e0 = *(const float4*)(er);
    e1 = *(const float4*)(er + 4);
    e2 = *(const float4*)(er + 32);
    e3 = *(const float4*)(er + 36);
    const float wf = __int_as_float(r4.w);
    int sj[4], dj[4];
    float wj[4];
#pragma unroll
    for (int j = 0; j < 4; ++j) {
      sj[j] = __shfl(r4.x, rbase + j, 16);
      dj[j] = __shfl(r4.y, rbase + j, 16);
      wj[j] = __shfl(wf, rbase + j, 16);
    }
    sp = make_int4(sj[0], sj[1], sj[2], sj[3]);
    dp = make_int4(dj[0], dj[1], dj[2], dj[3]);
    wq = make_float4(wj[0], wj[1], wj[2], wj[3]);
    const float* p0 = P + (size_t)sp.x * H + col0;
    const float* p1 = P + (size_t)sp.y * H + col0;
    const float* p2 = P + (size_t)sp.z * H + col0;
    const float* p3 = P + (size_t)sp.w * H + col0;
    pv[0] = p0[0]; pv[4] = p0[16];
    pv[1] = p1[0]; pv[5] = p1[16];
    pv[2] = p2[0]; pv[6] = p2[16];
    pv[3] = p3[0]; pv[7] = p3[16];
  };
  auto COMP = [&](const float4& e0, const float4& e1, const float4& e2,
                  const float4& e3, const float* pv, const int4& dp,
                  const float4& wq) {
    bf16x8 A0, A1;
    A0[0] = f2bf(e0.x); A0[1] = f2bf(e0.y); A0[2] = f2bf(e0.z); A0[3] = f2bf(e0.w);
    A0[4] = f2bf(e1.x); A0[5] = f2bf(e1.y); A0[6] = f2bf(e1.z); A0[7] = f2bf(e1.w);
    A1[0] = f2bf(e2.x); A1[1] = f2bf(e2.y); A1[2] = f2bf(e2.z); A1[3] = f2bf(e2.w);
    A1[4] = f2bf(e3.x); A1[5] = f2bf(e3.y); A1[6] = f2bf(e3.z); A1[7] = f2bf(e3.w);
    f32x4 C0 = {0.f, 0.f, 0.f, 0.f};
    C0 = __builtin_amdgcn_mfma_f32_16x16x32_bf16(A0, bw0, C0, 0, 0, 0);
    C0 = __builtin_amdgcn_mfma_f32_16x16x32_bf16(A1, bw1, C0, 0, 0, 0);
    f32x4 C1 = {0.f, 0.f, 0.f, 0.f};
    C1 = __builtin_amdgcn_mfma_f32_16x16x32_bf16(A0, bw2, C1, 0, 0, 0);
    C1 = __builtin_amdgcn_mfma_f32_16x16x32_bf16(A1, bw3, C1, 0, 0, 0);
    const float wqa[4] = {wq.x, wq.y, wq.z, wq.w};
    const int dls[4] = {dp.x - n0, dp.y - n0, dp.z - n0, dp.w - n0};
    int dl[5];
#pragma unroll
    for (int j = 0; j < 4; ++j)
      dl[j] = ((unsigned)dls[j] < (unsigned)NPB) ? dls[j] : NPB;
    dl[4] = -1;
    float c0v = 0.f, c1v = 0.f;
#pragma unroll
    for (int j = 0; j < 4; ++j) {
      c0v += C0[j] * pv[j] * wqa[j];
      c1v += C1[j] * pv[4 + j] * wqa[j];
      if (dl[j + 1] != dl[j]) {
        float* a0 = arep + dl[j] * 132 + col0;
        a0[0] += c0v;
        a0[16] += c1v;
        c0v = 0.f;
        c1v = 0.f;
      }
    }
  };

  if (q1 > q0) {
    float4 eA0, eA1, eA2, eA3, eB0, eB1, eB2, eB3;
    int4 spA, dpA, spB, dpB;
    float4 wqA, wqB;
    float pvA[8], pvB[8];
    ISSUE(q0, eA0, eA1, eA2, eA3, spA, dpA, wqA, pvA);
    if (q0 + 1 < q1) ISSUE(q0 + 1, eB0, eB1, eB2, eB3, spB, dpB, wqB, pvB);
    for (int q = q0; q < q1; q += 2) {
      COMP(eA0, eA1, eA2, eA3, pvA, dpA, wqA);
      if (q + 2 < q1) ISSUE(q + 2, eA0, eA1, eA2, eA3, spA, dpA, wqA, pvA);
      if (q + 1 < q1) {
        COMP(eB0, eB1, eB2, eB3, pvB, dpB, wqB);
        if (q + 3 < q1) ISSUE(q + 3, eB0, eB1, eB2, eB3, spB, dpB, wqB, pvB);
      }
    }
  }
  __syncthreads();

  for (int n = w; n < NPB; n += 4) {
    const int node = n0 + n;
    if (node >= N) break;
    const int rb = n * 132 + lane;
    const float v0 = acc[rb] + acc[RPAD + rb] + acc[2 * RPAD + rb] +
                     acc[3 * RPAD + rb];
    const float v1 = acc[rb + 64] + acc[RPAD + rb + 64] +
                     acc[2 * RPAD + rb + 64] + acc[3 * RPAD + rb + 64];
    const size_t i0 = (size_t)node * H + lane;
    if (FUSE_LN) {
      float s = v0 + v1, q = v0 * v0 + v1 * v1;
#pragma unroll
      for (int m = 32; m; m >>= 1) {
        s += __shfl_xor(s, m, 64);
        q += __shfl_xor(q, m, 64);
      }
      const float mu = s * 0.0078125f;
      const float var = q * 0.0078125f - mu * mu;
      const float rs = rsqrtf(var + 1e-5f);
      out[i0] = base[i0] + (v0 - mu) * rs * g[lane] + bb[lane] + skip[i0];
      out[i0 + 64] =
          base[i0 + 64] + (v1 - mu) * rs * g[lane + 64] + bb[lane + 64] + skip[i0 + 64];
    } else {
      out[i0] = v0;
      out[i0 + 64] = v1;
    }
  }
}

// -------------------------------------------------------- conv3d via MFMA
__global__ __launch_bounds__(256, 2) void conv3d_mfma(
    const float* __restrict__ Min, const short* __restrict__ Ktb,
    const float* __restrict__ bias, float* __restrict__ Mout) {
  __shared__ short in_s[193 * 128];
  const int b = blockIdx.x >> 3;
  const int x = blockIdx.x & 7;
  const int t = threadIdx.x;
  const int w = t >> 6, lane = t & 63;
  const int l15 = lane & 15, lg = lane >> 4;

  if (t < 128) in_s[192 * 128 + t] = 0;
#pragma unroll
  for (int it = 0; it < 12; ++it) {
    const int gidx = it * 256 + t;
    const int r = gidx >> 4;
    const int ch = (gidx & 15) * 8;
    const int gx = x + (r >> 6) - 1;
    const int yz = r & 63;
    float4 v0 = make_float4(0.f, 0.f, 0.f, 0.f), v1 = v0;
    if (gx >= 0 && gx < 8) {
      const float* src = Min + ((size_t)((b * 8 + gx) * 64 + yz)) * H + ch;
      v0 = *(const float4*)(src);
      v1 = *(const float4*)(src + 4);
    }
    bf16x8 pk;
    pk[0] = f2bf(v0.x); pk[1] = f2bf(v0.y); pk[2] = f2bf(v0.z); pk[3] = f2bf(v0.w);
    pk[4] = f2bf(v1.x); pk[5] = f2bf(v1.y); pk[6] = f2bf(v1.z); pk[7] = f2bf(v1.w);
    const int byte0 = (r * 256 + ch * 2) ^ ((r & 7) << 4);
    *(bf16x8*)((char*)in_s + byte0) = pk;
  }
  __syncthreads();

  const int cb0 = 2 * w;
  f32x4 C[4][2];
#pragma unroll
  for (int mt = 0; mt < 4; ++mt) {
    C[mt][0] = (f32x4){0.f, 0.f, 0.f, 0.f};
    C[mt][1] = (f32x4){0.f, 0.f, 0.f, 0.f};
  }

  auto BP = [&](int u, int cbi) -> const bf16x8* {
    return (const bf16x8*)(Ktb + (((size_t)u * 8) + cb0 + cbi) * 64 * 8 +
                           (size_t)lane * 8);
  };
  bf16x8 Ba0 = *BP(0, 0), Ba1 = *BP(0, 1);
  for (int u = 0; u < 108; ++u) {
    const int un = min(u + 1, 107);
    const bf16x8 Bn0 = *BP(un, 0);
    const bf16x8 Bn1 = *BP(un, 1);
    const int tap = u >> 2, kb = u & 3;
    const int dx = tap / 9, dy = (tap / 3) % 3, dz = tap % 3;
#pragma unroll
    for (int mt = 0; mt < 4; ++mt) {
      const int v = mt * 16 + l15;
      const int y = v >> 3, z = v & 7;
      const int ny = y + dy - 1, nz = z + dz - 1;
      const bool ok = (ny >= 0 && ny < 8 && nz >= 0 && nz < 8);
      const int vrow = ok ? dx * 64 + ny * 8 + nz : 192;
      const int byte0 = ((vrow * 256 + kb * 64 + lg * 16) ^ ((vrow & 7) << 4));
      const bf16x8 A = *(const bf16x8*)((const char*)in_s + byte0);
      C[mt][0] = __builtin_amdgcn_mfma_f32_16x16x32_bf16(A, Ba0, C[mt][0], 0, 0, 0);
      C[mt][1] = __builtin_amdgcn_mfma_f32_16x16x32_bf16(A, Ba1, C[mt][1], 0, 0, 0);
    }
    Ba0 = Bn0;
    Ba1 = Bn1;
  }

  const float b0 = bias[cb0 * 16 + l15];
  const float b1 = bias[cb0 * 16 + 16 + l15];
  float* obase = Mout + ((size_t)((b * 8 + x) * 64)) * H;
#pragma unroll
  for (int mt = 0; mt < 4; ++mt)
#pragma unroll
    for (int j = 0; j < 4; ++j) {
      const int vox = mt * 16 + lg * 4 + j;
      float* op = obase + (size_t)vox * H + cb0 * 16 + l15;
      op[0] = C[mt][0][j] + b0;
      op[16] = C[mt][1][j] + b1;
    }
}

// ------------------------------------------------------------------ driver
extern "C" void kernel_launch(void* const* d_in, const int* in_sizes, int n_in,
                              void* d_out, int out_size, void* d_ws, size_t ws_size,
                              hipStream_t stream) {
  const float* a_x = (const float*)d_in[0];
  const float* m_x = (const float*)d_in[1];
  const int* aa_idx = (const int*)d_in[2];
  const int* a2m_src = (const int*)d_in[3];
  const int* a2m_dst = (const int*)d_in[4];
  const int* m2a_src = (const int*)d_in[5];
  const int* m2a_dst = (const int*)d_in[6];
  const float* aa_w = (const float*)d_in[7];
  const float* a2m_w = (const float*)d_in[8];
  const float* m2a_w = (const float*)d_in[9];
  const float* aa_ea = (const float*)d_in[10];
  const float* a2m_ea = (const float*)d_in[11];
  const float* m2a_ea = (const float*)d_in[12];
  const float* W_short = (const float*)d_in[13];
  const float* We_short = (const float*)d_in[14];
  const float* W_a2m = (const float*)d_in[15];
  const float* We_a2m = (const float*)d_in[16];
  const float* W_m2a = (const float*)d_in[17];
  const float* We_m2a = (const float*)d_in[18];
  const float* conv_k = (const float*)d_in[19];
  const float* conv_b = (const float*)d_in[20];
  const float* g_short = (const float*)d_in[21];
  const float* b_short = (const float*)d_in[22];
  const float* g_long = (const float*)d_in[23];
  const float* b_long = (const float*)d_in[24];
  const float* g_a2m = (const float*)d_in[25];
  const float* b_a2m = (const float*)d_in[26];
  const float* g_m2a = (const float*)d_in[27];
  const float* b_m2a = (const float*)d_in[28];

  const int NA = in_sizes[0] / H;
  const int NM = in_sizes[1] / H;
  const int E_AA = in_sizes[2] / 2;
  const int E_AM = in_sizes[3];
  const int E_MA = in_sizes[5];
  const int* aa_src = aa_idx;
  const int* aa_dst = aa_idx + E_AA;

  const int NB_A = (NA + 256) / 256;
  const int NB_M = (NM + 256) / 256;
  const int S1 = NB_A, S2 = NB_A + NB_M;
  const int NB_T = NB_A + NB_M + NB_A;
  const int OFF1 = S1 * 256, OFF2 = S2 * 256;

  float* ws = (float*)d_ws;
  float* p_buf = ws;                         // NA*H
  float* m1_buf = p_buf + (size_t)NA * H;    // NM*H
  float* m2_buf = m1_buf + (size_t)NM * H;   // NM*H
  float* a2_buf = m2_buf + (size_t)NM * H;   // NA*H
  float* a1_buf = a2_buf + (size_t)NA * H;   // NA*H : LN(a_x)
  short* web_aa = (short*)(a1_buf + (size_t)NA * H);
  short* web_a2m = web_aa + 8192;
  short* web_m2a = web_a2m + 8192;
  short* wb_s = web_m2a + 8192;
  short* wb_a2m = wb_s + 16384;
  short* wb_m2a = wb_a2m + 16384;
  short* ktb = wb_m2a + 16384;               // 442368 shorts
  int4* sde_aa = (int4*)(ktb + 442368);
  int4* sde_a2m = sde_aa + E_AA + 16;
  int4* sde_m2a = sde_a2m + E_AM + 16;
  int* iws = (int*)(sde_m2a + E_MA + 16);
  int* cnt = iws;       iws += NB_T * 256;
  int* cursor = iws;    iws += NB_T * 256;
  int* bsum = iws;      iws += 512;
  int* bpre = iws;      iws += 512;
  int* rp_aa = iws;     iws += NA + 1;
  int* rp_a2m = iws;    iws += NM + 1;
  int* rp_m2a = iws;    iws += NA + 1;

  float* out_a = (float*)d_out;
  float* out_m = out_a + (size_t)NA * H;

  // ---- independent prep
  pack_we3<<<12, 256, 0, stream>>>(We_short, We_a2m, We_m2a, web_aa, web_a2m,
                                   web_m2a);
  pack_w3<<<24, 256, 0, stream>>>(W_short, W_a2m, W_m2a, wb_s, wb_a2m, wb_m2a);
  pack_kt<<<(27 * 4 * 8 * 64 + 255) / 256, 256, 0, stream>>>(conv_k, ktb);
  ln_rows<<<NM, 128, 0, stream>>>(m_x, g_long, b_long, m1_buf, NM);
  conv3d_mfma<<<(NM / 64), 256, 0, stream>>>(m1_buf, ktb, conv_b, m2_buf);
  ln_rows<<<NA, 128, 0, stream>>>(a_x, g_short, b_short, a1_buf, NA);
  proj_mfma<<<(NA + 63) / 64, 256, 0, stream>>>(a1_buf, wb_s, p_buf, NA);

  // ---- fused 3-set CSR build + permute
  hipMemsetAsync(cnt, 0, (size_t)NB_T * 256 * sizeof(int), stream);
  k_hist3<<<2048, 256, 0, stream>>>(aa_dst, a2m_dst, m2a_dst, E_AA, E_AM, E_MA,
                                    cnt, OFF1, OFF2);
  k_blocksum<<<NB_T, 256, 0, stream>>>(cnt, bsum);
  k_scan512<<<1, 512, 0, stream>>>(bsum, bpre, NB_T);
  k_apply3<<<NB_T, 256, 0, stream>>>(cnt, bpre, rp_aa, rp_a2m, rp_m2a, cursor,
                                     NA, NM, NA, S1, S2);
  k_perm3x<<<2048, 256, 0, stream>>>(aa_dst, aa_src, aa_w, a2m_dst, a2m_src,
                                     a2m_w, m2a_dst, m2a_src, m2a_w, E_AA,
                                     E_AM, E_MA, cursor, OFF1, OFF2, sde_aa,
                                     sde_a2m, sde_m2a);

  // ---- AA
  gather_mfma<16, false><<<(NA + 15) / 16, 256, 0, stream>>>(
      p_buf, web_aa, aa_ea, sde_aa, rp_aa, NA, nullptr, nullptr, nullptr,
      nullptr, a2_buf);

  // ---- a2m
  proj_mfma<<<(NA + 63) / 64, 256, 0, stream>>>(a2_buf, wb_a2m, p_buf, NA);
  gather_mfma<16, true><<<(NM + 15) / 16, 256, 0, stream>>>(
      p_buf, web_a2m, a2m_ea, sde_a2m, rp_a2m, NM, m2_buf, m_x, g_a2m, b_a2m,
      out_m);

  // ---- m2a
  proj_mfma<<<(NM + 63) / 64, 256, 0, stream>>>(m2_buf, wb_m2a, m1_buf, NM);
  gather_mfma<16, true><<<(NA + 15) / 16, 256, 0, stream>>>(
      m1_buf, web_m2a, m2a_ea, sde_m2a, rp_m2a, NA, a2_buf, a_x, g_m2a, b_m2a,
      out_a);
}

// Round 15
// 547.078 us; speedup vs baseline: 1.1353x; 1.1353x over previous
//
#include <hip/hip_runtime.h>
#include <hip/hip_bf16.h>

#define H 128
#define RBF 64

typedef __attribute__((ext_vector_type(8))) short bf16x8;
typedef __attribute__((ext_vector_type(4))) float f32x4;

__device__ inline short f2bf(float f) {
  union { float f; unsigned u; } v; v.f = f;
  const unsigned r = (v.u + 0x7FFFu + ((v.u >> 16) & 1u)) >> 16;
  return (short)r;
}

// --------------------------- fused LN for both node sets (one launch)
__global__ __launch_bounds__(128) void ln_rows2(
    const float* __restrict__ Xm, const float* __restrict__ gm,
    const float* __restrict__ bm, float* __restrict__ Ym, int NMr,
    const float* __restrict__ Xa, const float* __restrict__ ga,
    const float* __restrict__ ba, float* __restrict__ Ya) {
  __shared__ float sh[4];
  const int row = blockIdx.x;
  const float* X; const float* g; const float* bb; float* Y; int r;
  if (row < NMr) { X = Xm; g = gm; bb = bm; Y = Ym; r = row; }
  else { X = Xa; g = ga; bb = ba; Y = Ya; r = row - NMr; }
  const int j = threadIdx.x;
  float x = X[(size_t)r * H + j];
  float s = x, q = x * x;
#pragma unroll
  for (int m = 32; m; m >>= 1) {
    s += __shfl_xor(s, m, 64);
    q += __shfl_xor(q, m, 64);
  }
  if ((j & 63) == 0) { sh[(j >> 6) * 2] = s; sh[(j >> 6) * 2 + 1] = q; }
  __syncthreads();
  s = sh[0] + sh[2];
  q = sh[1] + sh[3];
  const float mu = s * 0.0078125f;
  const float var = q * 0.0078125f - mu * mu;
  const float rs = rsqrtf(var + 1e-5f);
  Y[(size_t)r * H + j] = (x - mu) * rs * g[j] + bb[j];
}

// conv_k (o,i,tap) -> MFMA B-frag bf16 directly
__global__ __launch_bounds__(256) void pack_kt(const float* __restrict__ K,
                                               short* __restrict__ Ktb) {
  const int id = blockIdx.x * 256 + threadIdx.x;
  if (id >= 27 * 4 * 8 * 64) return;
  const int l = id & 63;
  int r = id >> 6;
  const int cb = r & 7; r >>= 3;
  const int kb = r & 3;
  const int tap = r >> 2;
  const int o = cb * 16 + (l & 15);
  const int i0 = kb * 32 + (l >> 4) * 8;
  short* out = Ktb + (size_t)id * 8;
#pragma unroll
  for (int j = 0; j < 8; ++j)
    out[j] = f2bf(K[((size_t)o * H + i0 + j) * 27 + tap]);
}

// 3x We[64][128] f32 -> frag-layout bf16 in one launch
__global__ __launch_bounds__(256) void pack_we3(
    const float* __restrict__ We0, const float* __restrict__ We1,
    const float* __restrict__ We2, short* __restrict__ Wb0,
    short* __restrict__ Wb1, short* __restrict__ Wb2) {
  const int id = blockIdx.x * 256 + threadIdx.x;
  if (id >= 3072) return;
  const int which = id >> 10;
  const int i = id & 1023;
  const float* We = which == 0 ? We0 : which == 1 ? We1 : We2;
  short* Web = which == 0 ? Wb0 : which == 1 ? Wb1 : Wb2;
  const int f = i >> 6, l = i & 63;
  const int h = f >> 3, c = f & 7;
  const int col = (c << 4) + (l & 15);
  const int k0 = h * 32 + (l >> 4) * 8;
  short* o = Web + (size_t)i * 8;
#pragma unroll
  for (int j = 0; j < 8; ++j) o[j] = f2bf(We[(k0 + j) * H + col]);
}

// 3x W[128][128] f32 -> B-frag bf16 (frag f = kb*8+cb, kb=0..3)
__global__ __launch_bounds__(256) void pack_w3(
    const float* __restrict__ W0, const float* __restrict__ W1,
    const float* __restrict__ W2, short* __restrict__ Wb0,
    short* __restrict__ Wb1, short* __restrict__ Wb2) {
  const int id = blockIdx.x * 256 + threadIdx.x;
  if (id >= 3 * 2048) return;
  const int which = id >> 11;
  const int i = id & 2047;
  const float* W = which == 0 ? W0 : which == 1 ? W1 : W2;
  short* Wb = which == 0 ? Wb0 : which == 1 ? Wb1 : Wb2;
  const int f = i >> 6, l = i & 63;
  const int kb = f >> 3, cb = f & 7;
  const int col = cb * 16 + (l & 15);
  const int k0 = kb * 32 + (l >> 4) * 8;
  short* o = Wb + (size_t)i * 8;
#pragma unroll
  for (int j = 0; j < 8; ++j) o[j] = f2bf(W[(size_t)(k0 + j) * H + col]);
}

// -------------------------------------- fused 3-set counting-sort (CSR)
__global__ __launch_bounds__(256) void k_hist3(
    const int* __restrict__ d0, const int* __restrict__ d1,
    const int* __restrict__ d2, int E0, int E1, int E2,
    int* __restrict__ cnt, int off1, int off2) {
  int i = blockIdx.x * 256 + threadIdx.x;
  const int stride = gridDim.x * 256;
  const int ET = E0 + E1 + E2;
  for (; i < ET; i += stride) {
    int d, off;
    if (i < E0) { d = d0[i]; off = 0; }
    else if (i < E0 + E1) { d = d1[i - E0]; off = off1; }
    else { d = d2[i - E0 - E1]; off = off2; }
    atomicAdd(&cnt[off + d], 1);
  }
}

__global__ __launch_bounds__(256) void k_blocksum(const int* __restrict__ cnt,
                                                  int* __restrict__ bsum) {
  __shared__ int sh[256];
  const int t = threadIdx.x;
  sh[t] = cnt[blockIdx.x * 256 + t];
  __syncthreads();
#pragma unroll
  for (int o = 128; o; o >>= 1) {
    if (t < o) sh[t] += sh[t + o];
    __syncthreads();
  }
  if (!t) bsum[blockIdx.x] = sh[0];
}

__global__ __launch_bounds__(512) void k_scan512(const int* __restrict__ bsum,
                                                 int* __restrict__ bpre, int NB) {
  __shared__ int sh[512];
  const int t = threadIdx.x;
  const int v = (t < NB) ? bsum[t] : 0;
  sh[t] = v;
  __syncthreads();
  for (int o = 1; o < 512; o <<= 1) {
    const int u = (t >= o) ? sh[t - o] : 0;
    __syncthreads();
    sh[t] += u;
    __syncthreads();
  }
  if (t < NB) bpre[t] = sh[t] - v;
}

__global__ __launch_bounds__(256) void k_apply3(
    const int* __restrict__ cnt, const int* __restrict__ bpre,
    int* __restrict__ rp0, int* __restrict__ rp1, int* __restrict__ rp2,
    int* __restrict__ cursor, int N0, int N1, int N2, int S1, int S2) {
  __shared__ int sh[256];
  const int b = blockIdx.x;
  const int t = threadIdx.x;
  const int gi = b * 256 + t;
  const int v = cnt[gi];
  sh[t] = v;
  __syncthreads();
  for (int o = 1; o < 256; o <<= 1) {
    const int u = (t >= o) ? sh[t - o] : 0;
    __syncthreads();
    sh[t] += u;
    __syncthreads();
  }
  int sb, N;
  int* rp;
  if (b < S1) { sb = 0; N = N0; rp = rp0; }
  else if (b < S2) { sb = S1; N = N1; rp = rp1; }
  else { sb = S2; N = N2; rp = rp2; }
  const int excl = sh[t] - v + bpre[b] - bpre[sb];
  const int il = (b - sb) * 256 + t;
  if (il <= N) {
    rp[il] = excl;
    if (il < N) cursor[gi] = excl;
  }
}

// ---- wave-cooperative permute + bf16 convert + ew premultiply (one set)
__global__ __launch_bounds__(256) void k_perm2w(
    const int* __restrict__ dst, const int* __restrict__ src,
    const float* __restrict__ ew, const float* __restrict__ ea, int E,
    int* __restrict__ cursor, int2* __restrict__ sd,
    short* __restrict__ eapfp) {
  const int lane = threadIdx.x & 63;
  const int wid = blockIdx.x * 4 + (threadIdx.x >> 6);
  const int nw = gridDim.x * 4;
  if (blockIdx.x == 0 && threadIdx.x < 16)
    sd[E + threadIdx.x] = make_int2(0, -1);  // tail-tile pad -> dump row
  const int r = lane >> 2;
  const int c = lane & 3;
  for (int ebase = wid * 16; ebase < E; ebase += nw * 16) {
    const int ecnt = min(16, E - ebase);
    int p = 0;
    float w = 0.f;
    if (lane < ecnt) {
      const int e = ebase + lane;
      const int d = dst[e];
      w = ew[e];
      p = atomicAdd(&cursor[d], 1);
      sd[p] = make_int2(src[e], d);
    }
    const int pr = __shfl(p, r, 64);
    const float wr = __shfl(w, r, 64);
    if (r < ecnt) {
      const float* er = ea + ((size_t)(ebase + r)) * RBF + c * 16;
      const float4 x0 = *(const float4*)(er);
      const float4 x1 = *(const float4*)(er + 4);
      const float4 x2 = *(const float4*)(er + 8);
      const float4 x3 = *(const float4*)(er + 12);
      bf16x8 o0, o1;
      o0[0] = f2bf(x0.x * wr); o0[1] = f2bf(x0.y * wr);
      o0[2] = f2bf(x0.z * wr); o0[3] = f2bf(x0.w * wr);
      o0[4] = f2bf(x1.x * wr); o0[5] = f2bf(x1.y * wr);
      o0[6] = f2bf(x1.z * wr); o0[7] = f2bf(x1.w * wr);
      o1[0] = f2bf(x2.x * wr); o1[1] = f2bf(x2.y * wr);
      o1[2] = f2bf(x2.z * wr); o1[3] = f2bf(x2.w * wr);
      o1[4] = f2bf(x3.x * wr); o1[5] = f2bf(x3.y * wr);
      o1[6] = f2bf(x3.z * wr); o1[7] = f2bf(x3.w * wr);
      short* ob = eapfp + (size_t)pr * RBF + c * 16;
      *(bf16x8*)(ob) = o0;
      *(bf16x8*)(ob + 8) = o1;
    }
  }
}

// ---- same, fused over TWO edge sets (a2m + m2a share one launch)
__global__ __launch_bounds__(256) void k_perm2w2(
    const int* __restrict__ d1, const int* __restrict__ s1,
    const float* __restrict__ w1, const float* __restrict__ ea1, int E1,
    int* __restrict__ cur1, int2* __restrict__ sd1, short* __restrict__ ep1,
    const int* __restrict__ d2, const int* __restrict__ s2,
    const float* __restrict__ w2, const float* __restrict__ ea2, int E2,
    int* __restrict__ cur2, int2* __restrict__ sd2, short* __restrict__ ep2) {
  const int lane = threadIdx.x & 63;
  const int wid = blockIdx.x * 4 + (threadIdx.x >> 6);
  const int nw = gridDim.x * 4;
  if (blockIdx.x == 0 && threadIdx.x < 32) {
    const int wsel = threadIdx.x >> 4;
    const int j = threadIdx.x & 15;
    int2* sp = wsel == 0 ? sd1 + E1 : sd2 + E2;
    sp[j] = make_int2(0, -1);
  }
  const int T1 = (E1 + 15) >> 4;
  const int T2 = (E2 + 15) >> 4;
  const int TT = T1 + T2;
  const int r = lane >> 2;
  const int c = lane & 3;
  for (int tt = wid; tt < TT; tt += nw) {
    const int* dst; const int* src; const float* ew; const float* ea;
    int* cur; int2* sd; short* ep; int ebase, E;
    if (tt < T1) {
      dst = d1; src = s1; ew = w1; ea = ea1; cur = cur1; sd = sd1; ep = ep1;
      ebase = tt * 16; E = E1;
    } else {
      dst = d2; src = s2; ew = w2; ea = ea2; cur = cur2; sd = sd2; ep = ep2;
      ebase = (tt - T1) * 16; E = E2;
    }
    const int ecnt = min(16, E - ebase);
    int p = 0;
    float w = 0.f;
    if (lane < ecnt) {
      const int e = ebase + lane;
      const int d = dst[e];
      w = ew[e];
      p = atomicAdd(&cur[d], 1);
      sd[p] = make_int2(src[e], d);
    }
    const int pr = __shfl(p, r, 64);
    const float wr = __shfl(w, r, 64);
    if (r < ecnt) {
      const float* er = ea + ((size_t)(ebase + r)) * RBF + c * 16;
      const float4 x0 = *(const float4*)(er);
      const float4 x1 = *(const float4*)(er + 4);
      const float4 x2 = *(const float4*)(er + 8);
      const float4 x3 = *(const float4*)(er + 12);
      bf16x8 o0, o1;
      o0[0] = f2bf(x0.x * wr); o0[1] = f2bf(x0.y * wr);
      o0[2] = f2bf(x0.z * wr); o0[3] = f2bf(x0.w * wr);
      o0[4] = f2bf(x1.x * wr); o0[5] = f2bf(x1.y * wr);
      o0[6] = f2bf(x1.z * wr); o0[7] = f2bf(x1.w * wr);
      o1[0] = f2bf(x2.x * wr); o1[1] = f2bf(x2.y * wr);
      o1[2] = f2bf(x2.z * wr); o1[3] = f2bf(x2.w * wr);
      o1[4] = f2bf(x3.x * wr); o1[5] = f2bf(x3.y * wr);
      o1[6] = f2bf(x3.z * wr); o1[7] = f2bf(x3.w * wr);
      short* ob = ep + (size_t)pr * RBF + c * 16;
      *(bf16x8*)(ob) = o0;
      *(bf16x8*)(ob + 8) = o1;
    }
  }
}

// ------------------------------ projection via MFMA: Y = X @ W (bf16/f32acc)
__global__ __launch_bounds__(256, 2) void proj_mfma(
    const float* __restrict__ X, const short* __restrict__ Wb,
    float* __restrict__ Y, int N) {
  __shared__ short xs[64 * 128];  // bf16, XOR-swizzled rows
  const int row0 = blockIdx.x * 64;
  const int t = threadIdx.x;
  const int w = t >> 6, lane = t & 63;
  const int l15 = lane & 15, lg = lane >> 4;

#pragma unroll
  for (int it = 0; it < 4; ++it) {
    const int gidx = it * 256 + t;
    const int r = gidx >> 4;
    const int ch = (gidx & 15) * 8;
    const int row = row0 + r;
    float4 v0 = make_float4(0.f, 0.f, 0.f, 0.f), v1 = v0;
    if (row < N) {
      const float* src = X + (size_t)row * H + ch;
      v0 = *(const float4*)(src);
      v1 = *(const float4*)(src + 4);
    }
    bf16x8 pk;
    pk[0] = f2bf(v0.x); pk[1] = f2bf(v0.y); pk[2] = f2bf(v0.z); pk[3] = f2bf(v0.w);
    pk[4] = f2bf(v1.x); pk[5] = f2bf(v1.y); pk[6] = f2bf(v1.z); pk[7] = f2bf(v1.w);
    const int byte0 = (r * 256 + ch * 2) ^ ((r & 7) << 4);
    *(bf16x8*)((char*)xs + byte0) = pk;
  }
  __syncthreads();

  const int cb0 = 2 * w;
  bf16x8 bw[4][2];
#pragma unroll
  for (int kb = 0; kb < 4; ++kb)
#pragma unroll
    for (int ci = 0; ci < 2; ++ci)
      bw[kb][ci] = *(const bf16x8*)(Wb + (((size_t)kb * 8 + cb0 + ci) * 64 +
                                          lane) * 8);

  f32x4 C[4][2];
#pragma unroll
  for (int mt = 0; mt < 4; ++mt) {
    C[mt][0] = (f32x4){0.f, 0.f, 0.f, 0.f};
    C[mt][1] = (f32x4){0.f, 0.f, 0.f, 0.f};
  }
#pragma unroll
  for (int kb = 0; kb < 4; ++kb) {
#pragma unroll
    for (int mt = 0; mt < 4; ++mt) {
      const int r = mt * 16 + l15;
      const int byte0 = (r * 256 + kb * 64 + lg * 16) ^ ((r & 7) << 4);
      const bf16x8 A = *(const bf16x8*)((const char*)xs + byte0);
      C[mt][0] = __builtin_amdgcn_mfma_f32_16x16x32_bf16(A, bw[kb][0], C[mt][0], 0, 0, 0);
      C[mt][1] = __builtin_amdgcn_mfma_f32_16x16x32_bf16(A, bw[kb][1], C[mt][1], 0, 0, 0);
    }
  }
#pragma unroll
  for (int mt = 0; mt < 4; ++mt)
#pragma unroll
    for (int j = 0; j < 4; ++j) {
      const int row = row0 + mt * 16 + lg * 4 + j;
      if (row < N) {
        float* yp = Y + (size_t)row * H + cb0 * 16 + l15;
        yp[0] = C[mt][0][j];
        yp[16] = C[mt][1][j];
      }
    }
}

// ----------------------------------------- tiled MFMA edge gather (CSR)
// bf16 A-frags from eapfp; lg-replicated LDS acc (no atomics); 3-deep
// register pipeline. R15: 4 blocks/CU (LDS 36.4KB x4 = 145KB fits).
template <int NPB, bool FUSE_LN>
__global__ __launch_bounds__(256, 4) void gather_mfma(
    const float* __restrict__ P, const short* __restrict__ Web,
    const short* __restrict__ eapfp, const int2* __restrict__ sd,
    const int* __restrict__ rowptr, int N, const float* __restrict__ base,
    const float* __restrict__ skip, const float* __restrict__ g,
    const float* __restrict__ bb, float* __restrict__ out) {
  constexpr int RSTR = (NPB + 1) * 132;
  constexpr int RPAD = RSTR + ((16 - (RSTR & 31)) & 31);  // ≡16 (mod 32)
  __shared__ float acc[4 * RPAD];
  const int t = threadIdx.x;
  const int w = t >> 6, lane = t & 63;
  const int n0 = blockIdx.x * NPB;
  for (int u = t; u < 4 * RPAD; u += 256) acc[u] = 0.f;
  const int rp0 = rowptr[n0];
  const int rp1 = rowptr[min(n0 + NPB, N)];
  __syncthreads();
  const int q0 = rp0 >> 4;
  const int q1 = (rp1 + 15) >> 4;

  const int c0 = 2 * w;
  const bf16x8 bw0 = *(const bf16x8*)(Web + ((size_t)((0 + c0) * 64 + lane)) * 8);
  const bf16x8 bw1 = *(const bf16x8*)(Web + ((size_t)((8 + c0) * 64 + lane)) * 8);
  const bf16x8 bw2 = *(const bf16x8*)(Web + ((size_t)((1 + c0) * 64 + lane)) * 8);
  const bf16x8 bw3 = *(const bf16x8*)(Web + ((size_t)((9 + c0) * 64 + lane)) * 8);

  const int l15 = lane & 15, lg = lane >> 4, rbase = lg * 4;
  const int col0 = c0 * 16 + l15;
  float* const arep = acc + lg * RPAD;

  auto LOAD = [&](int q, bf16x8& A0, bf16x8& A1, int4& sp, int4& dp,
                  float* pv) {
    const short* fb = eapfp + ((size_t)(q * 16 + l15)) * RBF + lg * 8;
    A0 = *(const bf16x8*)(fb);
    A1 = *(const bf16x8*)(fb + 32);
    const int4 sd01 = *(const int4*)(sd + (size_t)(q * 16 + rbase));
    const int4 sd23 = *(const int4*)(sd + (size_t)(q * 16 + rbase + 2));
    sp = make_int4(sd01.x, sd01.z, sd23.x, sd23.z);
    dp = make_int4(sd01.y, sd01.w, sd23.y, sd23.w);
    const float* p0 = P + (size_t)sp.x * H + col0;
    const float* p1 = P + (size_t)sp.y * H + col0;
    const float* p2 = P + (size_t)sp.z * H + col0;
    const float* p3 = P + (size_t)sp.w * H + col0;
    pv[0] = p0[0]; pv[4] = p0[16];
    pv[1] = p1[0]; pv[5] = p1[16];
    pv[2] = p2[0]; pv[6] = p2[16];
    pv[3] = p3[0]; pv[7] = p3[16];
  };
  auto COMP = [&](const bf16x8& A0, const bf16x8& A1, const float* pv,
                  const int4& dp) {
    f32x4 C0 = {0.f, 0.f, 0.f, 0.f};
    C0 = __builtin_amdgcn_mfma_f32_16x16x32_bf16(A0, bw0, C0, 0, 0, 0);
    C0 = __builtin_amdgcn_mfma_f32_16x16x32_bf16(A1, bw1, C0, 0, 0, 0);
    f32x4 C1 = {0.f, 0.f, 0.f, 0.f};
    C1 = __builtin_amdgcn_mfma_f32_16x16x32_bf16(A0, bw2, C1, 0, 0, 0);
    C1 = __builtin_amdgcn_mfma_f32_16x16x32_bf16(A1, bw3, C1, 0, 0, 0);
    const int dls[4] = {dp.x - n0, dp.y - n0, dp.z - n0, dp.w - n0};
    int dl[5];
#pragma unroll
    for (int j = 0; j < 4; ++j)
      dl[j] = ((unsigned)dls[j] < (unsigned)NPB) ? dls[j] : NPB;
    dl[4] = -1;
    float c0v = 0.f, c1v = 0.f;
#pragma unroll
    for (int j = 0; j < 4; ++j) {
      c0v += C0[j] * pv[j];
      c1v += C1[j] * pv[4 + j];
      if (dl[j + 1] != dl[j]) {
        float* a0 = arep + dl[j] * 132 + col0;
        a0[0] += c0v;
        a0[16] += c1v;
        c0v = 0.f;
        c1v = 0.f;
      }
    }
  };

  if (q1 > q0) {
    bf16x8 A0a, A1a, A0b, A1b, A0c, A1c;
    int4 spa, dpa, spb, dpb, spc, dpc;
    float pva[8], pvb[8], pvc[8];
    LOAD(q0, A0a, A1a, spa, dpa, pva);
    if (q0 + 1 < q1) LOAD(q0 + 1, A0b, A1b, spb, dpb, pvb);
    int q = q0;
    while (true) {
      if (q + 2 < q1) LOAD(q + 2, A0c, A1c, spc, dpc, pvc);
      COMP(A0a, A1a, pva, dpa);
      if (++q >= q1) break;
      if (q + 2 < q1) LOAD(q + 2, A0a, A1a, spa, dpa, pva);
      COMP(A0b, A1b, pvb, dpb);
      if (++q >= q1) break;
      if (q + 2 < q1) LOAD(q + 2, A0b, A1b, spb, dpb, pvb);
      COMP(A0c, A1c, pvc, dpc);
      if (++q >= q1) break;
    }
  }
  __syncthreads();

  for (int n = w; n < NPB; n += 4) {
    const int node = n0 + n;
    if (node >= N) break;
    const int rb = n * 132 + lane;
    const float v0 = acc[rb] + acc[RPAD + rb] + acc[2 * RPAD + rb] +
                     acc[3 * RPAD + rb];
    const float v1 = acc[rb + 64] + acc[RPAD + rb + 64] +
                     acc[2 * RPAD + rb + 64] + acc[3 * RPAD + rb + 64];
    const size_t i0 = (size_t)node * H + lane;
    if (FUSE_LN) {
      float s = v0 + v1, q = v0 * v0 + v1 * v1;
#pragma unroll
      for (int m = 32; m; m >>= 1) {
        s += __shfl_xor(s, m, 64);
        q += __shfl_xor(q, m, 64);
      }
      const float mu = s * 0.0078125f;
      const float var = q * 0.0078125f - mu * mu;
      const float rs = rsqrtf(var + 1e-5f);
      out[i0] = base[i0] + (v0 - mu) * rs * g[lane] + bb[lane] + skip[i0];
      out[i0 + 64] =
          base[i0 + 64] + (v1 - mu) * rs * g[lane + 64] + bb[lane + 64] + skip[i0 + 64];
    } else {
      out[i0] = v0;
      out[i0 + 64] = v1;
    }
  }
}

// -------------------------------------------------------- conv3d via MFMA
__global__ __launch_bounds__(256, 2) void conv3d_mfma(
    const float* __restrict__ Min, const short* __restrict__ Ktb,
    const float* __restrict__ bias, float* __restrict__ Mout) {
  __shared__ short in_s[193 * 128];
  const int b = blockIdx.x >> 3;
  const int x = blockIdx.x & 7;
  const int t = threadIdx.x;
  const int w = t >> 6, lane = t & 63;
  const int l15 = lane & 15, lg = lane >> 4;

  if (t < 128) in_s[192 * 128 + t] = 0;
#pragma unroll
  for (int it = 0; it < 12; ++it) {
    const int gidx = it * 256 + t;
    const int r = gidx >> 4;
    const int ch = (gidx & 15) * 8;
    const int gx = x + (r >> 6) - 1;
    const int yz = r & 63;
    float4 v0 = make_float4(0.f, 0.f, 0.f, 0.f), v1 = v0;
    if (gx >= 0 && gx < 8) {
      const float* src = Min + ((size_t)((b * 8 + gx) * 64 + yz)) * H + ch;
      v0 = *(const float4*)(src);
      v1 = *(const float4*)(src + 4);
    }
    bf16x8 pk;
    pk[0] = f2bf(v0.x); pk[1] = f2bf(v0.y); pk[2] = f2bf(v0.z); pk[3] = f2bf(v0.w);
    pk[4] = f2bf(v1.x); pk[5] = f2bf(v1.y); pk[6] = f2bf(v1.z); pk[7] = f2bf(v1.w);
    const int byte0 = (r * 256 + ch * 2) ^ ((r & 7) << 4);
    *(bf16x8*)((char*)in_s + byte0) = pk;
  }
  __syncthreads();

  const int cb0 = 2 * w;
  f32x4 C[4][2];
#pragma unroll
  for (int mt = 0; mt < 4; ++mt) {
    C[mt][0] = (f32x4){0.f, 0.f, 0.f, 0.f};
    C[mt][1] = (f32x4){0.f, 0.f, 0.f, 0.f};
  }

  auto BP = [&](int u, int cbi) -> const bf16x8* {
    return (const bf16x8*)(Ktb + (((size_t)u * 8) + cb0 + cbi) * 64 * 8 +
                           (size_t)lane * 8);
  };
  bf16x8 Ba0 = *BP(0, 0), Ba1 = *BP(0, 1);
  for (int u = 0; u < 108; ++u) {
    const int un = min(u + 1, 107);
    const bf16x8 Bn0 = *BP(un, 0);
    const bf16x8 Bn1 = *BP(un, 1);
    const int tap = u >> 2, kb = u & 3;
    const int dx = tap / 9, dy = (tap / 3) % 3, dz = tap % 3;
#pragma unroll
    for (int mt = 0; mt < 4; ++mt) {
      const int v = mt * 16 + l15;
      const int y = v >> 3, z = v & 7;
      const int ny = y + dy - 1, nz = z + dz - 1;
      const bool ok = (ny >= 0 && ny < 8 && nz >= 0 && nz < 8);
      const int vrow = ok ? dx * 64 + ny * 8 + nz : 192;
      const int byte0 = ((vrow * 256 + kb * 64 + lg * 16) ^ ((vrow & 7) << 4));
      const bf16x8 A = *(const bf16x8*)((const char*)in_s + byte0);
      C[mt][0] = __builtin_amdgcn_mfma_f32_16x16x32_bf16(A, Ba0, C[mt][0], 0, 0, 0);
      C[mt][1] = __builtin_amdgcn_mfma_f32_16x16x32_bf16(A, Ba1, C[mt][1], 0, 0, 0);
    }
    Ba0 = Bn0;
    Ba1 = Bn1;
  }

  const float b0 = bias[cb0 * 16 + l15];
  const float b1 = bias[cb0 * 16 + 16 + l15];
  float* obase = Mout + ((size_t)((b * 8 + x) * 64)) * H;
#pragma unroll
  for (int mt = 0; mt < 4; ++mt)
#pragma unroll
    for (int j = 0; j < 4; ++j) {
      const int vox = mt * 16 + lg * 4 + j;
      float* op = obase + (size_t)vox * H + cb0 * 16 + l15;
      op[0] = C[mt][0][j] + b0;
      op[16] = C[mt][1][j] + b1;
    }
}

// ------------------------------------------------------------------ driver
extern "C" void kernel_launch(void* const* d_in, const int* in_sizes, int n_in,
                              void* d_out, int out_size, void* d_ws, size_t ws_size,
                              hipStream_t stream) {
  const float* a_x = (const float*)d_in[0];
  const float* m_x = (const float*)d_in[1];
  const int* aa_idx = (const int*)d_in[2];
  const int* a2m_src = (const int*)d_in[3];
  const int* a2m_dst = (const int*)d_in[4];
  const int* m2a_src = (const int*)d_in[5];
  const int* m2a_dst = (const int*)d_in[6];
  const float* aa_w = (const float*)d_in[7];
  const float* a2m_w = (const float*)d_in[8];
  const float* m2a_w = (const float*)d_in[9];
  const float* aa_ea = (const float*)d_in[10];
  const float* a2m_ea = (const float*)d_in[11];
  const float* m2a_ea = (const float*)d_in[12];
  const float* W_short = (const float*)d_in[13];
  const float* We_short = (const float*)d_in[14];
  const float* W_a2m = (const float*)d_in[15];
  const float* We_a2m = (const float*)d_in[16];
  const float* W_m2a = (const float*)d_in[17];
  const float* We_m2a = (const float*)d_in[18];
  const float* conv_k = (const float*)d_in[19];
  const float* conv_b = (const float*)d_in[20];
  const float* g_short = (const float*)d_in[21];
  const float* b_short = (const float*)d_in[22];
  const float* g_long = (const float*)d_in[23];
  const float* b_long = (const float*)d_in[24];
  const float* g_a2m = (const float*)d_in[25];
  const float* b_a2m = (const float*)d_in[26];
  const float* g_m2a = (const float*)d_in[27];
  const float* b_m2a = (const float*)d_in[28];

  const int NA = in_sizes[0] / H;
  const int NM = in_sizes[1] / H;
  const int E_AA = in_sizes[2] / 2;
  const int E_AM = in_sizes[3];
  const int E_MA = in_sizes[5];
  const int* aa_src = aa_idx;
  const int* aa_dst = aa_idx + E_AA;

  const int NB_A = (NA + 256) / 256;
  const int NB_M = (NM + 256) / 256;
  const int S1 = NB_A, S2 = NB_A + NB_M;
  const int NB_T = NB_A + NB_M + NB_A;
  const int OFF1 = S1 * 256, OFF2 = S2 * 256;

  float* ws = (float*)d_ws;
  float* p_buf = ws;                         // NA*H
  float* m1_buf = p_buf + (size_t)NA * H;    // NM*H
  float* m2_buf = m1_buf + (size_t)NM * H;   // NM*H
  float* a2_buf = m2_buf + (size_t)NM * H;   // NA*H
  float* a1_buf = a2_buf + (size_t)NA * H;   // NA*H : LN(a_x)
  short* web_aa = (short*)(a1_buf + (size_t)NA * H);
  short* web_a2m = web_aa + 8192;
  short* web_m2a = web_a2m + 8192;
  short* wb_s = web_m2a + 8192;
  short* wb_a2m = wb_s + 16384;
  short* wb_m2a = wb_a2m + 16384;
  short* ktb = wb_m2a + 16384;               // 442368 shorts
  short* eapfp = ktb + 442368;               // E_AA*64 shorts (shared region)
  short* ep_a2m = eapfp;                     // after AA gather: a2m half
  short* ep_m2a = eapfp + (size_t)E_AM * RBF;  // + m2a half (fits: E_AM+E_MA==E_AA)
  int2* sd_aa = (int2*)(eapfp + (size_t)E_AA * RBF);
  int2* sd_a2m = sd_aa + E_AA + 16;
  int2* sd_m2a = sd_a2m + E_AM + 16;
  int* iws = (int*)(sd_m2a + E_MA + 16);
  int* cnt = iws;       iws += NB_T * 256;
  int* cursor = iws;    iws += NB_T * 256;
  int* bsum = iws;      iws += 512;
  int* bpre = iws;      iws += 512;
  int* rp_aa = iws;     iws += NA + 1;
  int* rp_a2m = iws;    iws += NM + 1;
  int* rp_m2a = iws;    iws += NA + 1;

  float* out_a = (float*)d_out;
  float* out_m = out_a + (size_t)NA * H;

  // ---- independent prep
  pack_we3<<<12, 256, 0, stream>>>(We_short, We_a2m, We_m2a, web_aa, web_a2m,
                                   web_m2a);
  pack_w3<<<24, 256, 0, stream>>>(W_short, W_a2m, W_m2a, wb_s, wb_a2m, wb_m2a);
  pack_kt<<<(27 * 4 * 8 * 64 + 255) / 256, 256, 0, stream>>>(conv_k, ktb);
  ln_rows2<<<NM + NA, 128, 0, stream>>>(m_x, g_long, b_long, m1_buf, NM, a_x,
                                        g_short, b_short, a1_buf);
  conv3d_mfma<<<(NM / 64), 256, 0, stream>>>(m1_buf, ktb, conv_b, m2_buf);
  proj_mfma<<<(NA + 63) / 64, 256, 0, stream>>>(a1_buf, wb_s, p_buf, NA);

  // ---- fused 3-set CSR build
  hipMemsetAsync(cnt, 0, (size_t)NB_T * 256 * sizeof(int), stream);
  k_hist3<<<2048, 256, 0, stream>>>(aa_dst, a2m_dst, m2a_dst, E_AA, E_AM, E_MA,
                                    cnt, OFF1, OFF2);
  k_blocksum<<<NB_T, 256, 0, stream>>>(cnt, bsum);
  k_scan512<<<1, 512, 0, stream>>>(bsum, bpre, NB_T);
  k_apply3<<<NB_T, 256, 0, stream>>>(cnt, bpre, rp_aa, rp_a2m, rp_m2a, cursor,
                                     NA, NM, NA, S1, S2);

  // ---- AA
  k_perm2w<<<2048, 256, 0, stream>>>(aa_dst, aa_src, aa_w, aa_ea, E_AA, cursor,
                                     sd_aa, eapfp);
  gather_mfma<16, false><<<(NA + 15) / 16, 256, 0, stream>>>(
      p_buf, web_aa, eapfp, sd_aa, rp_aa, NA, nullptr, nullptr, nullptr,
      nullptr, a2_buf);

  // ---- fused a2m + m2a permute (two halves of the shared eapfp region)
  k_perm2w2<<<2048, 256, 0, stream>>>(
      a2m_dst, a2m_src, a2m_w, a2m_ea, E_AM, cursor + OFF1, sd_a2m, ep_a2m,
      m2a_dst, m2a_src, m2a_w, m2a_ea, E_MA, cursor + OFF2, sd_m2a, ep_m2a);

  // ---- a2m
  proj_mfma<<<(NA + 63) / 64, 256, 0, stream>>>(a2_buf, wb_a2m, p_buf, NA);
  gather_mfma<16, true><<<(NM + 15) / 16, 256, 0, stream>>>(
      p_buf, web_a2m, ep_a2m, sd_a2m, rp_a2m, NM, m2_buf, m_x, g_a2m, b_a2m,
      out_m);

  // ---- m2a
  proj_mfma<<<(NM + 63) / 64, 256, 0, stream>>>(m2_buf, wb_m2a, m1_buf, NM);
  gather_mfma<16, true><<<(NA + 15) / 16, 256, 0, stream>>>(
      m1_buf, web_m2a, ep_m2a, sd_m2a, rp_m2a, NA, a2_buf, a_x, g_m2a, b_m2a,
      out_a);
}